// Round 16
// baseline (244.306 us; speedup 1.0000x reference)
//
#include <hip/hip_runtime.h>
#include <hip/hip_fp16.h>
#include <math.h>

#define THREADS 256
#define CHUNK_SHIFT 14
#define CHUNK (1 << CHUNK_SHIFT)
#define LDS_WORDS 12500   // ceil(N/4) for N=50000, 8-bit packed counters

// ---- privatized LDS histogram, 4 bins/word (8-bit); dst blocks capture rank ----
__global__ __launch_bounds__(1024)
void k_hist(const int* __restrict__ src, const int* __restrict__ dst,
            unsigned int* __restrict__ partS, unsigned int* __restrict__ partD,
            unsigned char* __restrict__ rank, int E, int P, int words) {
    __shared__ unsigned int hist[LDS_WORDS];
    int isSrc = (blockIdx.x >= (unsigned)P);
    int b = isSrc ? (blockIdx.x - P) : blockIdx.x;
    int tid = threadIdx.x;

    for (int w = tid; w < words; w += 1024) hist[w] = 0u;
    __syncthreads();

    int start = b << CHUNK_SHIFT;
    int end = start + CHUNK; if (end > E) end = E;

    if (isSrc) {
        for (int e = start + tid; e < end; e += 1024) {
            int s = src[e];
            atomicAdd(&hist[s >> 2], 1u << ((s & 3) * 8));
        }
    } else {
        for (int e = start + tid; e < end; e += 1024) {
            int d = dst[e];
            unsigned int old = atomicAdd(&hist[d >> 2], 1u << ((d & 3) * 8));
            rank[e] = (unsigned char)((old >> ((d & 3) * 8)) & 0xFFu);
        }
    }
    __syncthreads();

    unsigned int* part = isSrc ? partS : partD;
    for (int w = tid; w < words; w += 1024)
        part[(size_t)b * words + w] = hist[w];
}

// ---- fused: per-node reduce (prefix -> SEPARATE prefD, no aliasing) + scan1 ----
__global__ __launch_bounds__(THREADS)
void k_pre(const unsigned int* __restrict__ partS,
           const unsigned int* __restrict__ partD,
           unsigned int* __restrict__ prefD,
           int* __restrict__ deg_d, float* __restrict__ ns, float* __restrict__ nd,
           int* __restrict__ rp, int* __restrict__ bsum,
           int P, int words, int N) {
    __shared__ int sdeg[THREADS];
    int t = threadIdx.x;
    int i = blockIdx.x * THREADS + t;

    int c = 0, s = 0;
    if (i < N) {
        int w = i >> 2;
        int sh = (i & 3) * 8;
        unsigned char* pB = (unsigned char*)prefD;
        for (int b = 0; b < P; b++) {
            size_t off = (size_t)b * words + w;
            unsigned int v = (partD[off] >> sh) & 0xFFu;
            pB[off * 4 + (i & 3)] = (unsigned char)c;   // excl prefix, byte lane
            c += (int)v;
        }
        for (int b = 0; b < P; b++)
            s += (int)((partS[(size_t)b * words + w] >> sh) & 0xFFu);
        deg_d[i] = c;
        nd[i] = c ? 1.0f / sqrtf((float)c) : 0.0f;
        ns[i] = s ? 1.0f / sqrtf((float)s) : 0.0f;
    }
    sdeg[t] = (i < N) ? c : 0;
    __syncthreads();

    int run = sdeg[t];
    for (int off = 1; off < THREADS; off <<= 1) {
        int x = (t >= off) ? sdeg[t - off] : 0;
        __syncthreads();
        sdeg[t] += x;
        __syncthreads();
    }
    if (i < N) rp[i] = sdeg[t] - run;
    if (t == THREADS - 1) bsum[blockIdx.x] = sdeg[t];
}

__global__ void k_scan2(int* __restrict__ bsum, int nb) {
    __shared__ int s[THREADS];
    int t = threadIdx.x;
    int v = (t < nb) ? bsum[t] : 0;
    s[t] = v;
    __syncthreads();
    for (int off = 1; off < THREADS; off <<= 1) {
        int x = (t >= off) ? s[t - off] : 0;
        __syncthreads();
        s[t] += x;
        __syncthreads();
    }
    if (t < nb) bsum[t] = s[t] - v;
}

// ---- CSR fill, atomic-free: rp + bsum + across-block prefix + local rank ----
__global__ void k_fill(const int* __restrict__ src, const int* __restrict__ dst,
                       const int* __restrict__ rp, const int* __restrict__ bsum,
                       const unsigned char* __restrict__ rank,
                       const unsigned int* __restrict__ prefD,
                       int* __restrict__ col, int E, int words) {
    int e = blockIdx.x * blockDim.x + threadIdx.x;
    if (e < E) {
        int d = dst[e];
        int b = e >> CHUNK_SHIFT;
        unsigned int pk = prefD[(size_t)b * words + (d >> 2)];
        int pref = (int)((pk >> ((d & 3) * 8)) & 0xFFu);
        col[rp[d] + bsum[d >> 8] + pref + (int)rank[e]] = src[e];
    }
}

// ---------------- H(fp16) = (X * norm_src) @ W   (64x64 tile, 4x4/thread) ----
#define XS_STRIDE 68
__global__ __launch_bounds__(256, 4)
void k_gemm64(const float* __restrict__ X, const float* __restrict__ norm,
              const float* __restrict__ W, __half* __restrict__ H, int N) {
    __shared__ float Xs[64 * XS_STRIDE];
    __shared__ float Ws[64 * 64];
    int tid = threadIdx.x;
    int rowBase = blockIdx.x * 64;

    for (int i = tid; i < 1024; i += 256)
        ((float4*)Ws)[i] = ((const float4*)W)[i];
    for (int i = tid; i < 1024; i += 256) {
        int r  = i >> 4;
        int k4 = i & 15;
        int row = rowBase + r;
        float4 v = make_float4(0.f, 0.f, 0.f, 0.f);
        if (row < N) {
            v = ((const float4*)X)[(size_t)row * 16 + k4];
            float nv = norm[row];
            v.x *= nv; v.y *= nv; v.z *= nv; v.w *= nv;
        }
        *((float4*)&Xs[r * XS_STRIDE + (k4 << 2)]) = v;
    }
    __syncthreads();

    int tc = tid & 15;
    int tr = tid >> 4;
    int c0 = tc * 4, r0 = tr * 4;
    float acc[4][4] = {};

#pragma unroll 2
    for (int k = 0; k < 64; k += 4) {
        float4 wv[4];
#pragma unroll
        for (int kk = 0; kk < 4; kk++)
            wv[kk] = *((const float4*)&Ws[(k + kk) * 64 + c0]);
#pragma unroll
        for (int j = 0; j < 4; j++) {
            float4 xv = *((const float4*)&Xs[(r0 + j) * XS_STRIDE + k]);
            acc[j][0] += xv.x * wv[0].x; acc[j][1] += xv.x * wv[0].y;
            acc[j][2] += xv.x * wv[0].z; acc[j][3] += xv.x * wv[0].w;
            acc[j][0] += xv.y * wv[1].x; acc[j][1] += xv.y * wv[1].y;
            acc[j][2] += xv.y * wv[1].z; acc[j][3] += xv.y * wv[1].w;
            acc[j][0] += xv.z * wv[2].x; acc[j][1] += xv.z * wv[2].y;
            acc[j][2] += xv.z * wv[2].z; acc[j][3] += xv.z * wv[2].w;
            acc[j][0] += xv.w * wv[3].x; acc[j][1] += xv.w * wv[3].y;
            acc[j][2] += xv.w * wv[3].z; acc[j][3] += xv.w * wv[3].w;
        }
    }
#pragma unroll
    for (int j = 0; j < 4; j++) {
        int row = rowBase + r0 + j;
        if (row < N) {
            __half2 h01 = __floats2half2_rn(acc[j][0], acc[j][1]);
            __half2 h23 = __floats2half2_rn(acc[j][2], acc[j][3]);
            uint2 pk;
            pk.x = *(unsigned int*)&h01;
            pk.y = *(unsigned int*)&h23;
            *((uint2*)(H + (size_t)row * 64 + c0)) = pk;
        }
    }
}

// ------- agg: Out[i,:] = tanh( nd[i] * sum_{e in row i} H[col[e], :] + b )
// Grid-stride + 2-deep software pipeline: iteration t issues idx load for
// node t+1 and meta loads for node t+2, then processes node t whose idx
// arrived during iteration t-1 -> per-node critical path = gather only.
__global__ __launch_bounds__(256)
void k_agg(const uint4* __restrict__ H4, const int* __restrict__ rp,
           const int* __restrict__ bsum, const int* __restrict__ deg,
           const int* __restrict__ col, const float* __restrict__ nd,
           const float* __restrict__ bias, float* __restrict__ Out, int N) {
    int wave = threadIdx.x >> 6;
    int lane = threadIdx.x & 63;
    int stride = gridDim.x * 4;
    int node = blockIdx.x * 4 + wave;
    if (node >= N) return;
    int g = lane >> 3;   // edge subgroup 0..7
    int l = lane & 7;    // uint4 index within 128B row

    // pipeline warm-up: meta+idx for node t, meta for node t+1
    int start0 = rp[node] + bsum[node >> 8];
    int n0 = deg[node];
    int idx0 = (lane < n0) ? col[start0 + lane] : 0;

    int node1 = node + stride;
    int start1 = 0, n1 = 0;
    if (node1 < N) { start1 = rp[node1] + bsum[node1 >> 8]; n1 = deg[node1]; }

    while (true) {
        // ---- prefetch: idx for t+1 (meta already resident), meta for t+2
        int idx1 = 0;
        if (node1 < N && lane < n1) idx1 = col[start1 + lane];
        int node2 = node1 + stride;
        int start2 = 0, n2 = 0;
        if (node2 < N) { start2 = rp[node2] + bsum[node2 >> 8]; n2 = deg[node2]; }

        // ---- process node t
        int sStart = __builtin_amdgcn_readfirstlane(start0);
        int sN     = __builtin_amdgcn_readfirstlane(n0);
        float a[8] = {0.f, 0.f, 0.f, 0.f, 0.f, 0.f, 0.f, 0.f};

        auto accum = [&](uint4 v) {
            float2 f0 = __half22float2(*(__half2*)&v.x);
            float2 f1 = __half22float2(*(__half2*)&v.y);
            float2 f2 = __half22float2(*(__half2*)&v.z);
            float2 f3 = __half22float2(*(__half2*)&v.w);
            a[0] += f0.x; a[1] += f0.y; a[2] += f1.x; a[3] += f1.y;
            a[4] += f2.x; a[5] += f2.y; a[6] += f3.x; a[7] += f3.y;
        };

        if (sN <= 32) {
            // fast path consumes prefetched idx0 directly
            int s0 = __shfl(idx0, g);
            uint4 z; z.x = 0u; z.y = 0u; z.z = 0u; z.w = 0u;
            uint4 v0 = z, v1 = z, v2 = z, v3 = z;
            if (g < sN) v0 = H4[(size_t)s0 * 8 + l];
            if (sN > 8) {
                int s1 = __shfl(idx0, 8 + g);
                if (8 + g < sN) v1 = H4[(size_t)s1 * 8 + l];
            }
            if (sN > 16) {
                int s2 = __shfl(idx0, 16 + g);
                if (16 + g < sN) v2 = H4[(size_t)s2 * 8 + l];
            }
            if (sN > 24) {
                int s3 = __shfl(idx0, 24 + g);
                if (24 + g < sN) v3 = H4[(size_t)s3 * 8 + l];
            }
            accum(v0);
            if (sN > 8)  accum(v1);
            if (sN > 16) accum(v2);
            if (sN > 24) accum(v3);
        } else {
            for (int base = 0; base < sN; base += 64) {
                int cnt = sN - base;
                if (cnt > 64) cnt = 64;
                int idx = (lane < cnt) ? col[sStart + base + lane] : 0;
                int j = 0;
                for (; j + 32 <= cnt; j += 32) {
                    int s0 = __shfl(idx, j + g);
                    int s1 = __shfl(idx, j + 8 + g);
                    int s2 = __shfl(idx, j + 16 + g);
                    int s3 = __shfl(idx, j + 24 + g);
                    uint4 v0 = H4[(size_t)s0 * 8 + l];
                    uint4 v1 = H4[(size_t)s1 * 8 + l];
                    uint4 v2 = H4[(size_t)s2 * 8 + l];
                    uint4 v3 = H4[(size_t)s3 * 8 + l];
                    accum(v0); accum(v1); accum(v2); accum(v3);
                }
                for (; j + 8 <= cnt; j += 8) {
                    int s0 = __shfl(idx, j + g);
                    uint4 v0 = H4[(size_t)s0 * 8 + l];
                    accum(v0);
                }
                int t = cnt - j;
                if (t > 0) {
                    int s0 = __shfl(idx, j + (g < t ? g : 0));
                    if (g < t) {
                        uint4 v0 = H4[(size_t)s0 * 8 + l];
                        accum(v0);
                    }
                }
            }
        }

        // ---- transpose-reduce: 3 butterfly steps -> one channel per lane
        int g0 = (lane >> 3) & 1, g1 = (lane >> 4) & 1, g2 = (lane >> 5) & 1;
        float b_[4];
#pragma unroll
        for (int j = 0; j < 4; j++) {
            float send = g0 ? a[j] : a[j + 4];
            float recv = __shfl_xor(send, 8);
            float keep = g0 ? a[j + 4] : a[j];
            b_[j] = keep + recv;
        }
        float c_[2];
#pragma unroll
        for (int j = 0; j < 2; j++) {
            float send = g1 ? b_[j] : b_[j + 2];
            float recv = __shfl_xor(send, 16);
            float keep = g1 ? b_[j + 2] : b_[j];
            c_[j] = keep + recv;
        }
        float send = g2 ? c_[0] : c_[1];
        float recv = __shfl_xor(send, 32);
        float keep = g2 ? c_[1] : c_[0];
        float s = keep + recv;

        int ch = (l << 3) + (g0 << 2) + (g1 << 1) + g2;
        float nv = nd[node];
        Out[(size_t)node * 64 + ch] = tanhf(s * nv + bias[ch]);

        // ---- rotate pipeline
        if (node1 >= N) break;
        node = node1; start0 = start1; n0 = n1; idx0 = idx1;
        node1 = node2; start1 = start2; n1 = n2;
    }
}

// ---------------- final FC: out = X @ Wfc + bfc  (64x10) ----------------
__global__ __launch_bounds__(640)
void k_fc(const float* __restrict__ X, const float* __restrict__ W,
          const float* __restrict__ b, float* __restrict__ out, int N) {
    __shared__ float Ws[640];
    __shared__ float bs[10];
    __shared__ float Xs[64 * 65];
    int tid = threadIdx.x;
    Ws[tid] = W[tid];
    if (tid < 10) bs[tid] = b[tid];
    int nodeBase = blockIdx.x * 64;
    for (int i = tid; i < 4096; i += 640) {
        int r = i >> 6, cc = i & 63;
        int nn = nodeBase + r;
        Xs[r * 65 + cc] = (nn < N) ? X[(size_t)nn * 64 + cc] : 0.0f;
    }
    __syncthreads();
    int ln = tid / 10, cl = tid % 10;
    float acc = bs[cl];
#pragma unroll
    for (int k = 0; k < 64; k++)
        acc += Xs[ln * 65 + k] * Ws[k * 10 + cl];
    int node = nodeBase + ln;
    if (node < N) out[(size_t)node * 10 + cl] = acc;
}

extern "C" void kernel_launch(void* const* d_in, const int* in_sizes, int n_in,
                              void* d_out, int out_size, void* d_ws, size_t ws_size,
                              hipStream_t stream) {
    const float* x   = (const float*)d_in[0];
    const int*   src = (const int*)d_in[1];
    const int*   dst = (const int*)d_in[2];
    const float* W1  = (const float*)d_in[3];
    const float* b1  = (const float*)d_in[4];
    const float* W2  = (const float*)d_in[5];
    const float* b2  = (const float*)d_in[6];
    const float* W3  = (const float*)d_in[7];
    const float* b3  = (const float*)d_in[8];
    const float* Wfc = (const float*)d_in[9];
    const float* bfc = (const float*)d_in[10];
    float* out = (float*)d_out;
    int N = in_sizes[0] / 64;
    int E = in_sizes[1];
    int P = (E + CHUNK - 1) >> CHUNK_SHIFT;   // hist blocks per direction
    int words = (N + 3) / 4;                  // packed 4 bins per u32

    char* ws = (char*)d_ws;
    size_t p = 0;
    auto alloc = [&](size_t bytes) -> void* {
        void* r = ws + p;
        p = (p + bytes + 255) & ~(size_t)255;
        return r;
    };
    int*    deg_d = (int*)alloc((size_t)N * 4);
    int*    rp    = (int*)alloc((size_t)N * 4);
    int*    bsum  = (int*)alloc((size_t)THREADS * 4);
    unsigned char* rank = (unsigned char*)alloc((size_t)E);
    int*    col   = (int*)alloc((size_t)E * 4);
    float*  ns    = (float*)alloc((size_t)N * 4);
    float*  nd    = (float*)alloc((size_t)N * 4);
    unsigned int* partS = (unsigned int*)alloc((size_t)P * words * 4);
    unsigned int* partD = (unsigned int*)alloc((size_t)P * words * 4);
    unsigned int* prefD = (unsigned int*)alloc((size_t)P * words * 4);
    __half* bufH  = (__half*)alloc((size_t)N * 64 * 2);
    float*  bufX  = (float*)alloc((size_t)N * 64 * 4);
    (void)ws_size; (void)n_in; (void)out_size;

    int gE = (E + THREADS - 1) / THREADS;
    int gN = (N + THREADS - 1) / THREADS;

    k_hist <<<2 * P, 1024, 0, stream>>>(src, dst, partS, partD, rank, E, P, words);
    k_pre  <<<gN, THREADS, 0, stream>>>(partS, partD, prefD, deg_d, ns, nd,
                                        rp, bsum, P, words, N);
    k_scan2<<<1,  THREADS, 0, stream>>>(bsum, gN);
    k_fill <<<gE, THREADS, 0, stream>>>(src, dst, rp, bsum, rank, prefD, col, E, words);

    int gG = (N + 63) / 64;
    int gA = 2048;                 // persistent grid-stride: 8 blocks/CU
    int gF = (N + 63) / 64;

    k_gemm64<<<gG, 256, 0, stream>>>(x,    ns, W1, bufH, N);
    k_agg   <<<gA, 256, 0, stream>>>((const uint4*)bufH, rp, bsum, deg_d, col, nd,
                                     b1, bufX, N);
    k_gemm64<<<gG, 256, 0, stream>>>(bufX, ns, W2, bufH, N);
    k_agg   <<<gA, 256, 0, stream>>>((const uint4*)bufH, rp, bsum, deg_d, col, nd,
                                     b2, bufX, N);
    k_gemm64<<<gG, 256, 0, stream>>>(bufX, ns, W3, bufH, N);
    k_agg   <<<gA, 256, 0, stream>>>((const uint4*)bufH, rp, bsum, deg_d, col, nd,
                                     b3, bufX, N);
    k_fc    <<<gF, 640, 0, stream>>>(bufX, Wfc, bfc, out, N);
}

// Round 17
// 230.854 us; speedup vs baseline: 1.0583x; 1.0583x over previous
//
#include <hip/hip_runtime.h>
#include <hip/hip_fp16.h>
#include <math.h>

#define THREADS 256
#define CHUNK_SHIFT 14
#define CHUNK (1 << CHUNK_SHIFT)
#define LDS_WORDS 12500   // ceil(N/4) for N=50000, 8-bit packed counters

// ---- privatized LDS histogram, 4 bins/word (8-bit); dst blocks capture rank ----
__global__ __launch_bounds__(1024)
void k_hist(const int* __restrict__ src, const int* __restrict__ dst,
            unsigned int* __restrict__ partS, unsigned int* __restrict__ partD,
            unsigned char* __restrict__ rank, int E, int P, int words) {
    __shared__ unsigned int hist[LDS_WORDS];
    int isSrc = (blockIdx.x >= (unsigned)P);
    int b = isSrc ? (blockIdx.x - P) : blockIdx.x;
    int tid = threadIdx.x;

    for (int w = tid; w < words; w += 1024) hist[w] = 0u;
    __syncthreads();

    int start = b << CHUNK_SHIFT;
    int end = start + CHUNK; if (end > E) end = E;

    if (isSrc) {
        for (int e = start + tid; e < end; e += 1024) {
            int s = src[e];
            atomicAdd(&hist[s >> 2], 1u << ((s & 3) * 8));
        }
    } else {
        for (int e = start + tid; e < end; e += 1024) {
            int d = dst[e];
            unsigned int old = atomicAdd(&hist[d >> 2], 1u << ((d & 3) * 8));
            rank[e] = (unsigned char)((old >> ((d & 3) * 8)) & 0xFFu);
        }
    }
    __syncthreads();

    unsigned int* part = isSrc ? partS : partD;
    for (int w = tid; w < words; w += 1024)
        part[(size_t)b * words + w] = hist[w];
}

// ---- fused: per-node reduce (prefix -> SEPARATE prefD, no aliasing) + scan1 ----
__global__ __launch_bounds__(THREADS)
void k_pre(const unsigned int* __restrict__ partS,
           const unsigned int* __restrict__ partD,
           unsigned int* __restrict__ prefD,
           int* __restrict__ deg_d, float* __restrict__ ns, float* __restrict__ nd,
           int* __restrict__ rp, int* __restrict__ bsum,
           int P, int words, int N) {
    __shared__ int sdeg[THREADS];
    int t = threadIdx.x;
    int i = blockIdx.x * THREADS + t;

    int c = 0, s = 0;
    if (i < N) {
        int w = i >> 2;
        int sh = (i & 3) * 8;
        unsigned char* pB = (unsigned char*)prefD;
        for (int b = 0; b < P; b++) {
            size_t off = (size_t)b * words + w;
            unsigned int v = (partD[off] >> sh) & 0xFFu;
            pB[off * 4 + (i & 3)] = (unsigned char)c;   // excl prefix, byte lane
            c += (int)v;
        }
        for (int b = 0; b < P; b++)
            s += (int)((partS[(size_t)b * words + w] >> sh) & 0xFFu);
        deg_d[i] = c;
        nd[i] = c ? 1.0f / sqrtf((float)c) : 0.0f;
        ns[i] = s ? 1.0f / sqrtf((float)s) : 0.0f;
    }
    sdeg[t] = (i < N) ? c : 0;
    __syncthreads();

    int run = sdeg[t];
    for (int off = 1; off < THREADS; off <<= 1) {
        int x = (t >= off) ? sdeg[t - off] : 0;
        __syncthreads();
        sdeg[t] += x;
        __syncthreads();
    }
    if (i < N) rp[i] = sdeg[t] - run;
    if (t == THREADS - 1) bsum[blockIdx.x] = sdeg[t];
}

__global__ void k_scan2(int* __restrict__ bsum, int nb) {
    __shared__ int s[THREADS];
    int t = threadIdx.x;
    int v = (t < nb) ? bsum[t] : 0;
    s[t] = v;
    __syncthreads();
    for (int off = 1; off < THREADS; off <<= 1) {
        int x = (t >= off) ? s[t - off] : 0;
        __syncthreads();
        s[t] += x;
        __syncthreads();
    }
    if (t < nb) bsum[t] = s[t] - v;
}

// ---- CSR fill, atomic-free: rp + bsum + across-block prefix + local rank ----
__global__ void k_fill(const int* __restrict__ src, const int* __restrict__ dst,
                       const int* __restrict__ rp, const int* __restrict__ bsum,
                       const unsigned char* __restrict__ rank,
                       const unsigned int* __restrict__ prefD,
                       int* __restrict__ col, int E, int words) {
    int e = blockIdx.x * blockDim.x + threadIdx.x;
    if (e < E) {
        int d = dst[e];
        int b = e >> CHUNK_SHIFT;
        unsigned int pk = prefD[(size_t)b * words + (d >> 2)];
        int pref = (int)((pk >> ((d & 3) * 8)) & 0xFFu);
        col[rp[d] + bsum[d >> 8] + pref + (int)rank[e]] = src[e];
    }
}

// ---------------- H(fp16) = (X * norm_src) @ W   (64x64 tile, 4x4/thread) ----
#define XS_STRIDE 68
__global__ __launch_bounds__(256, 4)
void k_gemm64(const float* __restrict__ X, const float* __restrict__ norm,
              const float* __restrict__ W, __half* __restrict__ H, int N) {
    __shared__ float Xs[64 * XS_STRIDE];
    __shared__ float Ws[64 * 64];
    int tid = threadIdx.x;
    int rowBase = blockIdx.x * 64;

    for (int i = tid; i < 1024; i += 256)
        ((float4*)Ws)[i] = ((const float4*)W)[i];
    for (int i = tid; i < 1024; i += 256) {
        int r  = i >> 4;
        int k4 = i & 15;
        int row = rowBase + r;
        float4 v = make_float4(0.f, 0.f, 0.f, 0.f);
        if (row < N) {
            v = ((const float4*)X)[(size_t)row * 16 + k4];
            float nv = norm[row];
            v.x *= nv; v.y *= nv; v.z *= nv; v.w *= nv;
        }
        *((float4*)&Xs[r * XS_STRIDE + (k4 << 2)]) = v;
    }
    __syncthreads();

    int tc = tid & 15;
    int tr = tid >> 4;
    int c0 = tc * 4, r0 = tr * 4;
    float acc[4][4] = {};

#pragma unroll 2
    for (int k = 0; k < 64; k += 4) {
        float4 wv[4];
#pragma unroll
        for (int kk = 0; kk < 4; kk++)
            wv[kk] = *((const float4*)&Ws[(k + kk) * 64 + c0]);
#pragma unroll
        for (int j = 0; j < 4; j++) {
            float4 xv = *((const float4*)&Xs[(r0 + j) * XS_STRIDE + k]);
            acc[j][0] += xv.x * wv[0].x; acc[j][1] += xv.x * wv[0].y;
            acc[j][2] += xv.x * wv[0].z; acc[j][3] += xv.x * wv[0].w;
            acc[j][0] += xv.y * wv[1].x; acc[j][1] += xv.y * wv[1].y;
            acc[j][2] += xv.y * wv[1].z; acc[j][3] += xv.y * wv[1].w;
            acc[j][0] += xv.z * wv[2].x; acc[j][1] += xv.z * wv[2].y;
            acc[j][2] += xv.z * wv[2].z; acc[j][3] += xv.z * wv[2].w;
            acc[j][0] += xv.w * wv[3].x; acc[j][1] += xv.w * wv[3].y;
            acc[j][2] += xv.w * wv[3].z; acc[j][3] += xv.w * wv[3].w;
        }
    }
#pragma unroll
    for (int j = 0; j < 4; j++) {
        int row = rowBase + r0 + j;
        if (row < N) {
            __half2 h01 = __floats2half2_rn(acc[j][0], acc[j][1]);
            __half2 h23 = __floats2half2_rn(acc[j][2], acc[j][3]);
            uint2 pk;
            pk.x = *(unsigned int*)&h01;
            pk.y = *(unsigned int*)&h23;
            *((uint2*)(H + (size_t)row * 64 + c0)) = pk;
        }
    }
}

// ------- agg: Out[i,:] = tanh( nd[i] * sum_{e in row i} H[col[e], :] + b )
// r15 structure (grid-stride persistent + meta prefetch) with two
// loop-invariant fixes: bias[ch] hoisted out of the node loop, and nd
// prefetched with the meta so its latency hides under the gathers.
__global__ __launch_bounds__(256)
void k_agg(const uint4* __restrict__ H4, const int* __restrict__ rp,
           const int* __restrict__ bsum, const int* __restrict__ deg,
           const int* __restrict__ col, const float* __restrict__ nd,
           const float* __restrict__ bias, float* __restrict__ Out, int N) {
    int wave = threadIdx.x >> 6;
    int lane = threadIdx.x & 63;
    int stride = gridDim.x * 4;
    int node = blockIdx.x * 4 + wave;
    if (node >= N) return;
    int g = lane >> 3;   // edge subgroup 0..7
    int l = lane & 7;    // uint4 index within 128B row

    // loop-invariant channel mapping + bias (per-lane constants)
    int g0 = (lane >> 3) & 1, g1 = (lane >> 4) & 1, g2 = (lane >> 5) & 1;
    int ch = (l << 3) + (g0 << 2) + (g1 << 1) + g2;
    float bv = bias[ch];

    // meta for first node (incl. nd)
    int start = rp[node] + bsum[node >> 8];
    int n = deg[node];
    float nv = nd[node];

    while (true) {
        // ---- prefetch next node's meta (independent; overlaps current gathers)
        int nextNode = node + stride;
        int nStart = 0, nN = 0;
        float nNv = 0.0f;
        if (nextNode < N) {
            nStart = rp[nextNode] + bsum[nextNode >> 8];
            nN = deg[nextNode];
            nNv = nd[nextNode];
        }

        int sStart = __builtin_amdgcn_readfirstlane(start);
        int sN     = __builtin_amdgcn_readfirstlane(n);
        float a[8] = {0.f, 0.f, 0.f, 0.f, 0.f, 0.f, 0.f, 0.f};

        auto accum = [&](uint4 v) {
            float2 f0 = __half22float2(*(__half2*)&v.x);
            float2 f1 = __half22float2(*(__half2*)&v.y);
            float2 f2 = __half22float2(*(__half2*)&v.z);
            float2 f3 = __half22float2(*(__half2*)&v.w);
            a[0] += f0.x; a[1] += f0.y; a[2] += f1.x; a[3] += f1.y;
            a[4] += f2.x; a[5] += f2.y; a[6] += f3.x; a[7] += f3.y;
        };

        if (sN <= 32) {
            int idx = (lane < sN) ? col[sStart + lane] : 0;
            int s0 = __shfl(idx, g);
            uint4 z; z.x = 0u; z.y = 0u; z.z = 0u; z.w = 0u;
            uint4 v0 = z, v1 = z, v2 = z, v3 = z;
            if (g < sN) v0 = H4[(size_t)s0 * 8 + l];
            if (sN > 8) {
                int s1 = __shfl(idx, 8 + g);
                if (8 + g < sN) v1 = H4[(size_t)s1 * 8 + l];
            }
            if (sN > 16) {
                int s2 = __shfl(idx, 16 + g);
                if (16 + g < sN) v2 = H4[(size_t)s2 * 8 + l];
            }
            if (sN > 24) {
                int s3 = __shfl(idx, 24 + g);
                if (24 + g < sN) v3 = H4[(size_t)s3 * 8 + l];
            }
            accum(v0);
            if (sN > 8)  accum(v1);
            if (sN > 16) accum(v2);
            if (sN > 24) accum(v3);
        } else {
            for (int base = 0; base < sN; base += 64) {
                int cnt = sN - base;
                if (cnt > 64) cnt = 64;
                int idx = (lane < cnt) ? col[sStart + base + lane] : 0;
                int j = 0;
                for (; j + 32 <= cnt; j += 32) {
                    int s0 = __shfl(idx, j + g);
                    int s1 = __shfl(idx, j + 8 + g);
                    int s2 = __shfl(idx, j + 16 + g);
                    int s3 = __shfl(idx, j + 24 + g);
                    uint4 v0 = H4[(size_t)s0 * 8 + l];
                    uint4 v1 = H4[(size_t)s1 * 8 + l];
                    uint4 v2 = H4[(size_t)s2 * 8 + l];
                    uint4 v3 = H4[(size_t)s3 * 8 + l];
                    accum(v0); accum(v1); accum(v2); accum(v3);
                }
                for (; j + 8 <= cnt; j += 8) {
                    int s0 = __shfl(idx, j + g);
                    uint4 v0 = H4[(size_t)s0 * 8 + l];
                    accum(v0);
                }
                int t = cnt - j;
                if (t > 0) {
                    int s0 = __shfl(idx, j + (g < t ? g : 0));
                    if (g < t) {
                        uint4 v0 = H4[(size_t)s0 * 8 + l];
                        accum(v0);
                    }
                }
            }
        }

        // ---- transpose-reduce: 3 butterfly steps -> one channel per lane
        float b_[4];
#pragma unroll
        for (int j = 0; j < 4; j++) {
            float send = g0 ? a[j] : a[j + 4];
            float recv = __shfl_xor(send, 8);
            float keep = g0 ? a[j + 4] : a[j];
            b_[j] = keep + recv;
        }
        float c_[2];
#pragma unroll
        for (int j = 0; j < 2; j++) {
            float send = g1 ? b_[j] : b_[j + 2];
            float recv = __shfl_xor(send, 16);
            float keep = g1 ? b_[j + 2] : b_[j];
            c_[j] = keep + recv;
        }
        float send = g2 ? c_[0] : c_[1];
        float recv = __shfl_xor(send, 32);
        float keep = g2 ? c_[1] : c_[0];
        float s = keep + recv;

        Out[(size_t)node * 64 + ch] = tanhf(s * nv + bv);

        if (nextNode >= N) break;
        node = nextNode; start = nStart; n = nN; nv = nNv;
    }
}

// ---------------- final FC: out = X @ Wfc + bfc  (64x10) ----------------
__global__ __launch_bounds__(640)
void k_fc(const float* __restrict__ X, const float* __restrict__ W,
          const float* __restrict__ b, float* __restrict__ out, int N) {
    __shared__ float Ws[640];
    __shared__ float bs[10];
    __shared__ float Xs[64 * 65];
    int tid = threadIdx.x;
    Ws[tid] = W[tid];
    if (tid < 10) bs[tid] = b[tid];
    int nodeBase = blockIdx.x * 64;
    for (int i = tid; i < 4096; i += 640) {
        int r = i >> 6, cc = i & 63;
        int nn = nodeBase + r;
        Xs[r * 65 + cc] = (nn < N) ? X[(size_t)nn * 64 + cc] : 0.0f;
    }
    __syncthreads();
    int ln = tid / 10, cl = tid % 10;
    float acc = bs[cl];
#pragma unroll
    for (int k = 0; k < 64; k++)
        acc += Xs[ln * 65 + k] * Ws[k * 10 + cl];
    int node = nodeBase + ln;
    if (node < N) out[(size_t)node * 10 + cl] = acc;
}

extern "C" void kernel_launch(void* const* d_in, const int* in_sizes, int n_in,
                              void* d_out, int out_size, void* d_ws, size_t ws_size,
                              hipStream_t stream) {
    const float* x   = (const float*)d_in[0];
    const int*   src = (const int*)d_in[1];
    const int*   dst = (const int*)d_in[2];
    const float* W1  = (const float*)d_in[3];
    const float* b1  = (const float*)d_in[4];
    const float* W2  = (const float*)d_in[5];
    const float* b2  = (const float*)d_in[6];
    const float* W3  = (const float*)d_in[7];
    const float* b3  = (const float*)d_in[8];
    const float* Wfc = (const float*)d_in[9];
    const float* bfc = (const float*)d_in[10];
    float* out = (float*)d_out;
    int N = in_sizes[0] / 64;
    int E = in_sizes[1];
    int P = (E + CHUNK - 1) >> CHUNK_SHIFT;   // hist blocks per direction
    int words = (N + 3) / 4;                  // packed 4 bins per u32

    char* ws = (char*)d_ws;
    size_t p = 0;
    auto alloc = [&](size_t bytes) -> void* {
        void* r = ws + p;
        p = (p + bytes + 255) & ~(size_t)255;
        return r;
    };
    int*    deg_d = (int*)alloc((size_t)N * 4);
    int*    rp    = (int*)alloc((size_t)N * 4);
    int*    bsum  = (int*)alloc((size_t)THREADS * 4);
    unsigned char* rank = (unsigned char*)alloc((size_t)E);
    int*    col   = (int*)alloc((size_t)E * 4);
    float*  ns    = (float*)alloc((size_t)N * 4);
    float*  nd    = (float*)alloc((size_t)N * 4);
    unsigned int* partS = (unsigned int*)alloc((size_t)P * words * 4);
    unsigned int* partD = (unsigned int*)alloc((size_t)P * words * 4);
    unsigned int* prefD = (unsigned int*)alloc((size_t)P * words * 4);
    __half* bufH  = (__half*)alloc((size_t)N * 64 * 2);
    float*  bufX  = (float*)alloc((size_t)N * 64 * 4);
    (void)ws_size; (void)n_in; (void)out_size;

    int gE = (E + THREADS - 1) / THREADS;
    int gN = (N + THREADS - 1) / THREADS;

    k_hist <<<2 * P, 1024, 0, stream>>>(src, dst, partS, partD, rank, E, P, words);
    k_pre  <<<gN, THREADS, 0, stream>>>(partS, partD, prefD, deg_d, ns, nd,
                                        rp, bsum, P, words, N);
    k_scan2<<<1,  THREADS, 0, stream>>>(bsum, gN);
    k_fill <<<gE, THREADS, 0, stream>>>(src, dst, rp, bsum, rank, prefD, col, E, words);

    int gG = (N + 63) / 64;
    int gA = 2048;                 // persistent grid-stride: 8 blocks/CU
    int gF = (N + 63) / 64;

    k_gemm64<<<gG, 256, 0, stream>>>(x,    ns, W1, bufH, N);
    k_agg   <<<gA, 256, 0, stream>>>((const uint4*)bufH, rp, bsum, deg_d, col, nd,
                                     b1, bufX, N);
    k_gemm64<<<gG, 256, 0, stream>>>(bufX, ns, W2, bufH, N);
    k_agg   <<<gA, 256, 0, stream>>>((const uint4*)bufH, rp, bsum, deg_d, col, nd,
                                     b2, bufX, N);
    k_gemm64<<<gG, 256, 0, stream>>>(bufX, ns, W3, bufH, N);
    k_agg   <<<gA, 256, 0, stream>>>((const uint4*)bufH, rp, bsum, deg_d, col, nd,
                                     b3, bufX, N);
    k_fc    <<<gF, 640, 0, stream>>>(bufX, Wfc, bfc, out, N);
}